// Round 1
// baseline (305.058 us; speedup 1.0000x reference)
//
#include <hip/hip_runtime.h>

#define BATCH 8
#define CH    256
#define NN    1024
#define DD    32

// ws layout (floats): q (B,32,N) | k (B,32,N) | v (B,256,N)
#define QOFF  0
#define KOFF  (BATCH * DD * NN)            // 262144
#define VOFF  (2 * BATCH * DD * NN)        // 524288

__device__ __forceinline__ constexpr float kScale() { return 0.17677669529663687f; } // 1/sqrt(32)
#define INV31 (1.0f / 31.0f)

// ---------------------------------------------------------------------------
// Kernel P: fused q/k/v projection.  Out[m,n] = W_all[m,:] . x[b,:,n] + bias
// m in [0,320): 0-31 -> Wq, 32-63 -> Wk, 64-319 -> Wv.
// Tile: 64(m) x 64(n), 256 threads, 4x4 per thread, K staged in 16-chunks.
// ---------------------------------------------------------------------------
__global__ __launch_bounds__(256) void proj_kernel(
    const float* __restrict__ x,
    const float* __restrict__ Wq, const float* __restrict__ bq,
    const float* __restrict__ Wk, const float* __restrict__ bk,
    const float* __restrict__ Wv, const float* __restrict__ bv,
    float* __restrict__ qkv)
{
    const int nt  = blockIdx.x;   // 0..15
    const int mt  = blockIdx.y;   // 0..4
    const int b   = blockIdx.z;   // 0..7
    const int tid = threadIdx.x;
    const int tx  = tid & 15;     // n-quad
    const int ty  = tid >> 4;     // m-quad

    __shared__ float Wt[16][68];  // [kk][mm] (transposed on load)
    __shared__ float Xt[16][68];  // [kk][nn]

    float acc[4][4];
#pragma unroll
    for (int i = 0; i < 4; i++)
#pragma unroll
        for (int j = 0; j < 4; j++) acc[i][j] = 0.f;

    const int n0 = nt * 64;
    const int m0 = mt * 64;

    for (int k0 = 0; k0 < CH; k0 += 16) {
        // stage W tile (transposed)
        {
            const int kk  = tid & 15;
            const int mmb = tid >> 4;  // 0..15
#pragma unroll
            for (int r = 0; r < 4; r++) {
                const int mm = mmb + r * 16;
                const int m  = m0 + mm;
                float w;
                if (m < 32)      w = Wq[m * CH + k0 + kk];
                else if (m < 64) w = Wk[(m - 32) * CH + k0 + kk];
                else             w = Wv[(m - 64) * CH + k0 + kk];
                Wt[kk][mm] = w;
            }
        }
        // stage X tile
        {
            const int nn  = tid & 63;
            const int kkb = tid >> 6;  // 0..3
#pragma unroll
            for (int r = 0; r < 4; r++) {
                const int kk = kkb + r * 4;
                Xt[kk][nn] = x[(size_t)(b * CH + k0 + kk) * NN + n0 + nn];
            }
        }
        __syncthreads();
#pragma unroll
        for (int kk = 0; kk < 16; kk++) {
            float4 a4 = *(const float4*)&Wt[kk][ty * 4];
            float4 b4 = *(const float4*)&Xt[kk][tx * 4];
            float a[4] = {a4.x, a4.y, a4.z, a4.w};
            float bb[4] = {b4.x, b4.y, b4.z, b4.w};
#pragma unroll
            for (int i = 0; i < 4; i++)
#pragma unroll
                for (int j = 0; j < 4; j++) acc[i][j] += a[i] * bb[j];
        }
        __syncthreads();
    }

    // epilogue: bias + store (float4)
#pragma unroll
    for (int i = 0; i < 4; i++) {
        const int m = m0 + ty * 4 + i;
        float bias;
        size_t off;
        if (m < 32)      { bias = bq[m];      off = QOFF + (size_t)(b * DD + m) * NN; }
        else if (m < 64) { bias = bk[m - 32]; off = KOFF + (size_t)(b * DD + (m - 32)) * NN; }
        else             { bias = bv[m - 64]; off = VOFF + (size_t)(b * CH + (m - 64)) * NN; }
        float4 r;
        r.x = acc[i][0] + bias;
        r.y = acc[i][1] + bias;
        r.z = acc[i][2] + bias;
        r.w = acc[i][3] + bias;
        *(float4*)&qkv[off + n0 + tx * 4] = r;
    }
}

// ---------------------------------------------------------------------------
// Kernel B: flash-style attention + PV + residual.
// One block = one (b, 32-row query tile). 256 blocks total (1/CU).
// logits s[i,j] = scale * ( q_i . k_j  -  u0_i * a_j  -  u1_i * b_j )
//   (all j-constant rp terms dropped: softmax-invariant)
// Online softmax over j-chunks of 32; PV accumulated as 8c x 4i per thread.
// ---------------------------------------------------------------------------
__global__ __launch_bounds__(256) void attn_kernel(
    const float* __restrict__ x,
    const float* __restrict__ Wr,
    const float* __restrict__ gamma,
    const float* __restrict__ qkv,
    float* __restrict__ out)
{
    const int it  = blockIdx.x;   // query tile 0..31
    const int b   = blockIdx.y;   // 0..7
    const int tid = threadIdx.x;
    const int i0  = it * 32;

    const float* q = qkv + QOFF + (size_t)(b * DD) * NN;
    const float* k = qkv + KOFF + (size_t)(b * DD) * NN;
    const float* v = qkv + VOFF + (size_t)(b * CH) * NN;

    __shared__ float qs[DD][33];    // [d][i_local]
    __shared__ float kt[DD][33];    // [d][j_local]
    __shared__ float Ps[32][36];    // scores -> probs
    __shared__ float Vt[CH][36];    // v chunk [c][j_local]
    __shared__ float u0s[32], u1s[32], m_s[32], l_s[32], alpha_s[32];

    // load q tile: qs[d][il] = q[d*N + i0+il]
    {
        const int il = tid & 31;
        const int d0 = tid >> 5;  // 0..7
#pragma unroll
        for (int r = 0; r < 4; r++) {
            const int dd = d0 + r * 8;
            qs[dd][il] = q[(size_t)dd * NN + i0 + il];
        }
    }
    __syncthreads();

    // u0/u1 per query row; init online-softmax state
    if (tid < 64) {
        const int il    = tid >> 1;
        const int which = tid & 1;
        float s = 0.f;
#pragma unroll
        for (int dd = 0; dd < DD; dd++) s += qs[dd][il] * Wr[dd * 2 + which];
        if (which == 0) u0s[il] = s; else u1s[il] = s;
    }
    if (tid < 32) { m_s[tid] = -1e30f; l_s[tid] = 0.f; }

    // phase-3 thread mapping: iq = i-quad (0..7), cg = c base (0..31)
    const int iq = tid & 7;
    const int cg = tid >> 3;

    float acc[8][4];
#pragma unroll
    for (int cc = 0; cc < 8; cc++)
#pragma unroll
        for (int ii = 0; ii < 4; ii++) acc[cc][ii] = 0.f;

    for (int j0 = 0; j0 < NN; j0 += 32) {
        __syncthreads();  // protect kt/Vt/Ps from previous-iteration readers

        // stage k chunk
        {
            const int jl = tid & 31;
            const int d0 = tid >> 5;
#pragma unroll
            for (int r = 0; r < 4; r++) {
                const int dd = d0 + r * 8;
                kt[dd][jl] = k[(size_t)dd * NN + j0 + jl];
            }
        }
        // stage V chunk
        {
            const int jl = tid & 31;
            const int c0 = tid >> 5;  // 0..7
            for (int c = c0; c < CH; c += 8)
                Vt[c][jl] = v[(size_t)c * NN + j0 + jl];
        }
        __syncthreads();

        // compute raw scores into Ps
        {
            const int jl  = tid & 31;
            const int i0l = tid >> 5;  // 0..7
            const int j   = j0 + jl;
            const float Aj = (float)(j >> 5) * INV31;
            const float Bj = (float)(j & 31) * INV31;
#pragma unroll
            for (int r = 0; r < 4; r++) {
                const int il = i0l + r * 8;
                float s = 0.f;
#pragma unroll
                for (int dd = 0; dd < DD; dd++) s += qs[dd][il] * kt[dd][jl];
                s -= u0s[il] * Aj + u1s[il] * Bj;
                Ps[il][jl] = s * kScale();
            }
        }
        __syncthreads();

        // online softmax per row (32 rows on 32 threads)
        if (tid < 32) {
            const int il = tid;
            const float mold = m_s[il];
            float mc = mold;
#pragma unroll
            for (int j = 0; j < 32; j++) mc = fmaxf(mc, Ps[il][j]);
            const float alpha = __expf(mold - mc);
            float lsum = 0.f;
#pragma unroll
            for (int j = 0; j < 32; j++) {
                const float p = __expf(Ps[il][j] - mc);
                Ps[il][j] = p;
                lsum += p;
            }
            m_s[il]     = mc;
            l_s[il]     = l_s[il] * alpha + lsum;
            alpha_s[il] = alpha;
        }
        __syncthreads();

        // rescale accumulators, then PV accumulate over this chunk
        float al[4];
#pragma unroll
        for (int ii = 0; ii < 4; ii++) al[ii] = alpha_s[iq * 4 + ii];
#pragma unroll
        for (int cc = 0; cc < 8; cc++)
#pragma unroll
            for (int ii = 0; ii < 4; ii++) acc[cc][ii] *= al[ii];

#pragma unroll
        for (int j4 = 0; j4 < 8; j4++) {
            float4 p4[4];
#pragma unroll
            for (int ii = 0; ii < 4; ii++)
                p4[ii] = *(const float4*)&Ps[iq * 4 + ii][j4 * 4];
#pragma unroll
            for (int cc = 0; cc < 8; cc++) {
                const float4 v4 = *(const float4*)&Vt[cc * 32 + cg][j4 * 4];
#pragma unroll
                for (int ii = 0; ii < 4; ii++) {
                    acc[cc][ii] += v4.x * p4[ii].x;
                    acc[cc][ii] += v4.y * p4[ii].y;
                    acc[cc][ii] += v4.z * p4[ii].z;
                    acc[cc][ii] += v4.w * p4[ii].w;
                }
            }
        }
    }

    // epilogue: out = gamma * (acc / l) + x    (float4 stores, fully coalesced)
    const float gam = gamma[0];
#pragma unroll
    for (int cc = 0; cc < 8; cc++) {
        const int c = cc * 32 + cg;
        const size_t off4 = (size_t)(b * CH + c) * NN + i0 + iq * 4;
        const float4 xr = *(const float4*)&x[off4];
        float4 r;
        r.x = gam * acc[cc][0] / l_s[iq * 4 + 0] + xr.x;
        r.y = gam * acc[cc][1] / l_s[iq * 4 + 1] + xr.y;
        r.z = gam * acc[cc][2] / l_s[iq * 4 + 2] + xr.z;
        r.w = gam * acc[cc][3] / l_s[iq * 4 + 3] + xr.w;
        *(float4*)&out[off4] = r;
    }
}

extern "C" void kernel_launch(void* const* d_in, const int* in_sizes, int n_in,
                              void* d_out, int out_size, void* d_ws, size_t ws_size,
                              hipStream_t stream) {
    (void)in_sizes; (void)n_in; (void)out_size; (void)ws_size;
    const float* x     = (const float*)d_in[0];
    const float* Wq    = (const float*)d_in[1];
    const float* bq    = (const float*)d_in[2];
    const float* Wk    = (const float*)d_in[3];
    const float* bk    = (const float*)d_in[4];
    const float* Wv    = (const float*)d_in[5];
    const float* bv    = (const float*)d_in[6];
    const float* Wr    = (const float*)d_in[7];
    // d_in[8] = br: contributes only a j-constant logit term -> softmax-invariant, dropped.
    const float* gamma = (const float*)d_in[9];
    float* out = (float*)d_out;
    float* qkv = (float*)d_ws;

    proj_kernel<<<dim3(16, 5, 8), 256, 0, stream>>>(x, Wq, bq, Wk, bk, Wv, bv, qkv);
    attn_kernel<<<dim3(32, 8), 256, 0, stream>>>(x, Wr, gamma, qkv, out);
}

// Round 2
// 149.646 us; speedup vs baseline: 2.0385x; 2.0385x over previous
//
#include <hip/hip_runtime.h>

#define BATCH 8
#define CH    256
#define NN    1024
#define DD    32

// ws layout (bf16 elements, i.e. unsigned short):
//   qT [b][i=1024][d=32]  (scale folded in)
//   kT [b][j=1024][d=32]  (rp folded in: k~ = k + bk - a_j*Wr0 - b_j*Wr1)
//   v  [b][c=256][j=1024] (bias folded in)
#define QT_OFF 0
#define KT_OFF (BATCH * NN * DD)       // 262144
#define V_OFF  (2 * BATCH * NN * DD)   // 524288  (total 2621440 shorts = 5 MB)

#define SCALE 0.17677669529663687f     // 1/sqrt(32)
#define INV31 (1.0f / 31.0f)

typedef __attribute__((ext_vector_type(4))) float f32x4;
typedef __attribute__((ext_vector_type(8))) short bf16x8;

__device__ __forceinline__ unsigned short f2bf(float x) {
    union { float f; unsigned int u; } v; v.f = x;
    return (unsigned short)((v.u + 0x7FFFu + ((v.u >> 16) & 1u)) >> 16);
}
__device__ __forceinline__ unsigned int packbf2(float lo, float hi) {
    return (unsigned int)f2bf(lo) | ((unsigned int)f2bf(hi) << 16);
}

// ---------------------------------------------------------------------------
// Kernel P: fused q/k/v projection -> bf16, with scale/rp/bias folding.
// m in [0,320): 0-31 -> q (written transposed), 32-63 -> k~ (transposed),
// 64-319 -> v (row-major). fp32 compute, 64x64 tiles, 4x4/thread.
// ---------------------------------------------------------------------------
__global__ __launch_bounds__(256) void proj_kernel(
    const float* __restrict__ x,
    const float* __restrict__ Wq, const float* __restrict__ bq,
    const float* __restrict__ Wk, const float* __restrict__ bk,
    const float* __restrict__ Wv, const float* __restrict__ bv,
    const float* __restrict__ Wr,
    unsigned short* __restrict__ ws)
{
    const int nt  = blockIdx.x;   // 0..15
    const int mt  = blockIdx.y;   // 0..4
    const int b   = blockIdx.z;   // 0..7
    const int tid = threadIdx.x;
    const int tx  = tid & 15;     // n-quad
    const int ty  = tid >> 4;     // m-quad

    __shared__ float Wt[16][68];  // [kk][mm]
    __shared__ float Xt[16][68];  // [kk][nn]

    float acc[4][4];
#pragma unroll
    for (int i = 0; i < 4; i++)
#pragma unroll
        for (int j = 0; j < 4; j++) acc[i][j] = 0.f;

    const int n0 = nt * 64;
    const int m0 = mt * 64;

    for (int k0 = 0; k0 < CH; k0 += 16) {
        {   // stage W tile (transposed)
            const int kk  = tid & 15;
            const int mmb = tid >> 4;
#pragma unroll
            for (int r = 0; r < 4; r++) {
                const int mm = mmb + r * 16;
                const int m  = m0 + mm;
                float w;
                if (m < 32)      w = Wq[m * CH + k0 + kk];
                else if (m < 64) w = Wk[(m - 32) * CH + k0 + kk];
                else             w = Wv[(m - 64) * CH + k0 + kk];
                Wt[kk][mm] = w;
            }
        }
        {   // stage X tile
            const int nn  = tid & 63;
            const int kkb = tid >> 6;
#pragma unroll
            for (int r = 0; r < 4; r++) {
                const int kk = kkb + r * 4;
                Xt[kk][nn] = x[(size_t)(b * CH + k0 + kk) * NN + n0 + nn];
            }
        }
        __syncthreads();
#pragma unroll
        for (int kk = 0; kk < 16; kk++) {
            float4 a4 = *(const float4*)&Wt[kk][ty * 4];
            float4 b4 = *(const float4*)&Xt[kk][tx * 4];
            float a[4] = {a4.x, a4.y, a4.z, a4.w};
            float bb[4] = {b4.x, b4.y, b4.z, b4.w};
#pragma unroll
            for (int i = 0; i < 4; i++)
#pragma unroll
                for (int j = 0; j < 4; j++) acc[i][j] += a[i] * bb[j];
        }
        __syncthreads();
    }

    // epilogue: fold bias/scale/rp, convert to bf16, store
#pragma unroll
    for (int i = 0; i < 4; i++) {
        const int m = m0 + ty * 4 + i;
#pragma unroll
        for (int j = 0; j < 4; j++) {
            const int n = n0 + tx * 4 + j;
            float val = acc[i][j];
            if (m < 32) {
                // qT[b][n][m], scale folded
                ws[QT_OFF + (size_t)(b * NN + n) * DD + m] = f2bf((val + bq[m]) * SCALE);
            } else if (m < 64) {
                const int d = m - 32;
                const float An = (float)(n >> 5) * INV31;
                const float Bn = (float)(n & 31) * INV31;
                val += bk[d] - An * Wr[d * 2] - Bn * Wr[d * 2 + 1];
                ws[KT_OFF + (size_t)(b * NN + n) * DD + d] = f2bf(val);
            } else {
                const int c = m - 64;
                ws[V_OFF + (size_t)(b * CH + c) * NN + n] = f2bf(val + bv[c]);
            }
        }
    }
}

// ---------------------------------------------------------------------------
// Kernel B: barrier-free MFMA flash attention.
// wave = (b, 16-row i-tile, 64-channel c-quarter); 512 blocks x 4 waves.
// QK^T as S^T (M=j, N=i): col = i = lane&15 -> softmax over j is in-lane
// 8-val max + shfl_xor(16,32). PV (M=c, N=i) shares col = i, so alpha
// rescale is a plain per-lane multiply. P C-layout -> B-operand via 8
// bpermutes of packed bf16 pairs. No LDS, no __syncthreads.
// ---------------------------------------------------------------------------
__global__ __launch_bounds__(256) void attn_kernel(
    const float* __restrict__ x,
    const float* __restrict__ gamma,
    const unsigned short* __restrict__ ws,
    float* __restrict__ out)
{
    const int it   = blockIdx.x;        // 0..63, i-tile of 16
    const int b    = blockIdx.y;        // 0..7
    const int tid  = threadIdx.x;
    const int wv   = tid >> 6;          // c-quarter 0..3
    const int lane = tid & 63;
    const int n    = lane & 15;         // col index: i
    const int q4   = lane >> 4;         // quad 0..3
    const int i0   = it * 16;
    const int cb   = wv * 64;

    const unsigned short* qT = ws + QT_OFF + (size_t)b * NN * DD;
    const unsigned short* kT = ws + KT_OFF + (size_t)b * NN * DD;
    const unsigned short* vp = ws + V_OFF  + (size_t)b * CH * NN;

    // q B-operand: B[k=d=8*q4+jj][n=i] = qT[i0+n][8*q4+jj]  (16B load, loop-invariant)
    const bf16x8 qf = *(const bf16x8*)(qT + (size_t)(i0 + n) * DD + q4 * 8);

    f32x4 acc[4];
#pragma unroll
    for (int t = 0; t < 4; t++) acc[t] = (f32x4){0.f, 0.f, 0.f, 0.f};
    float m_run = -1e30f;
    float l_run = 0.f;

    for (int j0 = 0; j0 < NN; j0 += 32) {
        // A-operands: k~ rows (M=j), V rows (M=c); all 16B contiguous
        const bf16x8 ka0 = *(const bf16x8*)(kT + (size_t)(j0 +      n) * DD + q4 * 8);
        const bf16x8 ka1 = *(const bf16x8*)(kT + (size_t)(j0 + 16 + n) * DD + q4 * 8);
        bf16x8 va[4];
#pragma unroll
        for (int t = 0; t < 4; t++)
            va[t] = *(const bf16x8*)(vp + (size_t)(cb + t * 16 + n) * NN + j0 + q4 * 8);

        const f32x4 z = {0.f, 0.f, 0.f, 0.f};
        f32x4 s0 = __builtin_amdgcn_mfma_f32_16x16x32_bf16(ka0, qf, z, 0, 0, 0);
        f32x4 s1 = __builtin_amdgcn_mfma_f32_16x16x32_bf16(ka1, qf, z, 0, 0, 0);
        // S^T[j][i]: row j = 16*tile + 4*q4 + r, col i = i0 + n

        // ---- online softmax over j (rows) for my column i ----
        float mc = fmaxf(fmaxf(fmaxf(s0[0], s0[1]), fmaxf(s0[2], s0[3])),
                         fmaxf(fmaxf(s1[0], s1[1]), fmaxf(s1[2], s1[3])));
        mc = fmaxf(mc, __shfl_xor(mc, 16, 64));
        mc = fmaxf(mc, __shfl_xor(mc, 32, 64));
        const float mnew  = fmaxf(m_run, mc);
        const float alpha = __expf(m_run - mnew);
        float p0[4], p1[4];
        float ls = 0.f;
#pragma unroll
        for (int r = 0; r < 4; r++) {
            p0[r] = __expf(s0[r] - mnew);
            p1[r] = __expf(s1[r] - mnew);
            ls += p0[r] + p1[r];
        }
        ls += __shfl_xor(ls, 16, 64);
        ls += __shfl_xor(ls, 32, 64);
        l_run = l_run * alpha + ls;
        m_run = mnew;

#pragma unroll
        for (int t = 0; t < 4; t++) acc[t] *= alpha;

        // ---- build PV B-operand P^T[k=j][n=i] from C-layout via bpermute ----
        // target: b32[t] = bf16 pair (P[j=8*q4+2t], P[j=8*q4+2t+1]) for col i.
        // source: tile tf=q4>>1, quad qs=2*(q4&1)+(t>>1), pair pp=t&1, lane qs*16+n.
        unsigned int pk0[2] = { packbf2(p0[0], p0[1]), packbf2(p0[2], p0[3]) };
        unsigned int pk1[2] = { packbf2(p1[0], p1[1]), packbf2(p1[2], p1[3]) };
        const int qh2 = (q4 & 1) * 2;
        union { unsigned int u[4]; bf16x8 v; } pf;
#pragma unroll
        for (int t = 0; t < 4; t++) {
            const int src = (qh2 + (t >> 1)) * 16 + n;
            const unsigned int lo = (unsigned int)__shfl((int)pk0[t & 1], src, 64);
            const unsigned int hi = (unsigned int)__shfl((int)pk1[t & 1], src, 64);
            pf.u[t] = (q4 >= 2) ? hi : lo;
        }

        // ---- PV: acc[c-tile] += V * P^T ----
#pragma unroll
        for (int t = 0; t < 4; t++)
            acc[t] = __builtin_amdgcn_mfma_f32_16x16x32_bf16(va[t], pf.v, acc[t], 0, 0, 0);
    }

    // epilogue: out = gamma * acc / l + x
    const float rl = gamma[0] / l_run;
#pragma unroll
    for (int t = 0; t < 4; t++) {
#pragma unroll
        for (int r = 0; r < 4; r++) {
            const int c = cb + t * 16 + q4 * 4 + r;
            const size_t idx = (size_t)(b * CH + c) * NN + i0 + n;
            out[idx] = acc[t][r] * rl + x[idx];
        }
    }
}

extern "C" void kernel_launch(void* const* d_in, const int* in_sizes, int n_in,
                              void* d_out, int out_size, void* d_ws, size_t ws_size,
                              hipStream_t stream) {
    (void)in_sizes; (void)n_in; (void)out_size; (void)ws_size;
    const float* x     = (const float*)d_in[0];
    const float* Wq    = (const float*)d_in[1];
    const float* bq    = (const float*)d_in[2];
    const float* Wk    = (const float*)d_in[3];
    const float* bk    = (const float*)d_in[4];
    const float* Wv    = (const float*)d_in[5];
    const float* bv    = (const float*)d_in[6];
    const float* Wr    = (const float*)d_in[7];
    // d_in[8] = br: j-constant logit shift -> softmax-invariant, dropped.
    const float* gamma = (const float*)d_in[9];
    float* out = (float*)d_out;
    unsigned short* ws = (unsigned short*)d_ws;

    proj_kernel<<<dim3(16, 5, 8), 256, 0, stream>>>(x, Wq, bq, Wk, bk, Wv, bv, Wr, ws);
    attn_kernel<<<dim3(64, 8), 256, 0, stream>>>(x, gamma, ws, out);
}

// Round 3
// 139.517 us; speedup vs baseline: 2.1865x; 1.0726x over previous
//
#include <hip/hip_runtime.h>
#include <hip/hip_bf16.h>

#define BATCH 8
#define CH    256
#define NN    1024
#define DD    32

// ws layout (bf16 shorts): qT [b][i][d] (scale folded) | kT [b][j][d] (rp+bias
// folded) | v [b][c][j] (bias folded). 5 MB total.
#define QT_OFF 0
#define KT_OFF (BATCH * NN * DD)
#define V_OFF  (2 * BATCH * NN * DD)

#define SCALE 0.17677669529663687f     // 1/sqrt(32)
#define INV31 (1.0f / 31.0f)

typedef __attribute__((ext_vector_type(4))) float f32x4;
typedef __attribute__((ext_vector_type(8))) short bf16x8;

__device__ __forceinline__ unsigned int packbf2(float lo, float hi) {
    __hip_bfloat162 h = __float22bfloat162_rn(make_float2(lo, hi));
    union { __hip_bfloat162 h; unsigned int u; } cv; cv.h = h;
    return cv.u;
}
__device__ __forceinline__ unsigned short f2bf(float x) {
    union { float f; unsigned int u; } v; v.f = x;
    return (unsigned short)((v.u + 0x7FFFu + ((v.u >> 16) & 1u)) >> 16);
}

// ---------------------------------------------------------------------------
// Kernel P: MFMA projection, no LDS, no barriers.
// Block = 320m x 16n for one batch; 4 waves, each 5 m-frags (80 m) x 16 n.
// A = W rows (fp32 -> bf16 packed cvt inline), B = x columns: B[k=c][n] is a
// 16-consecutive-float coalesced read of x[c][n0..n0+15]. Epilogue folds
// bias/scale/rp and emits bf16 qT/kT/v.
// ---------------------------------------------------------------------------
__global__ __launch_bounds__(256) void proj_kernel(
    const float* __restrict__ x,
    const float* __restrict__ Wq, const float* __restrict__ bq,
    const float* __restrict__ Wk, const float* __restrict__ bk,
    const float* __restrict__ Wv, const float* __restrict__ bv,
    const float* __restrict__ Wr,
    unsigned short* __restrict__ ws)
{
    const int nt   = blockIdx.x;   // 0..63
    const int b    = blockIdx.y;   // 0..7
    const int tid  = threadIdx.x;
    const int wv   = tid >> 6;     // 0..3 (m-group)
    const int lane = tid & 63;
    const int n16  = lane & 15;
    const int q4   = lane >> 4;
    const int n    = nt * 16 + n16;

    f32x4 acc[5];
#pragma unroll
    for (int t = 0; t < 5; t++) acc[t] = (f32x4){0.f, 0.f, 0.f, 0.f};

    // loop-invariant per-frag W row pointers (region is wave-uniform per frag)
    const float* wrow[5];
#pragma unroll
    for (int t = 0; t < 5; t++) {
        const int m = (wv * 5 + t) * 16 + n16;
        wrow[t] = (m < 32) ? (Wq + m * CH)
                : (m < 64) ? (Wk + (m - 32) * CH)
                           : (Wv + (m - 64) * CH);
    }

    for (int c0 = 0; c0 < CH; c0 += 32) {
        const int kofs = c0 + q4 * 8;
        // B-frag: x[b][kofs+jj][n], jj=0..7 (each load: 16 consecutive floats/quad)
        float bx[8];
#pragma unroll
        for (int jj = 0; jj < 8; jj++)
            bx[jj] = x[(size_t)(b * CH + kofs + jj) * NN + n];
        union { unsigned int u[4]; bf16x8 v; } bf;
#pragma unroll
        for (int p = 0; p < 4; p++) bf.u[p] = packbf2(bx[2 * p], bx[2 * p + 1]);

#pragma unroll
        for (int t = 0; t < 5; t++) {
            const float* wp = wrow[t] + kofs;
            const float4 a0 = *(const float4*)(wp);
            const float4 a1 = *(const float4*)(wp + 4);
            union { unsigned int u[4]; bf16x8 v; } af;
            af.u[0] = packbf2(a0.x, a0.y); af.u[1] = packbf2(a0.z, a0.w);
            af.u[2] = packbf2(a1.x, a1.y); af.u[3] = packbf2(a1.z, a1.w);
            acc[t] = __builtin_amdgcn_mfma_f32_16x16x32_bf16(af.v, bf.v, acc[t], 0, 0, 0);
        }
    }

    // epilogue: C rows m = mf*16 + q4*4 + r, col n
#pragma unroll
    for (int t = 0; t < 5; t++) {
        const int mf = wv * 5 + t;
        const int mb = mf * 16 + q4 * 4;
        if (mb < 32) {
            const float r0 = (acc[t][0] + bq[mb + 0]) * SCALE;
            const float r1 = (acc[t][1] + bq[mb + 1]) * SCALE;
            const float r2 = (acc[t][2] + bq[mb + 2]) * SCALE;
            const float r3 = (acc[t][3] + bq[mb + 3]) * SCALE;
            uint2 st = { packbf2(r0, r1), packbf2(r2, r3) };
            *(uint2*)(ws + QT_OFF + (size_t)(b * NN + n) * DD + mb) = st;
        } else if (mb < 64) {
            const int d = mb - 32;
            const float An = (float)(n >> 5) * INV31;
            const float Bn = (float)(n & 31) * INV31;
            float r[4];
#pragma unroll
            for (int rr = 0; rr < 4; rr++)
                r[rr] = acc[t][rr] + bk[d + rr] - An * Wr[2 * (d + rr)] - Bn * Wr[2 * (d + rr) + 1];
            uint2 st = { packbf2(r[0], r[1]), packbf2(r[2], r[3]) };
            *(uint2*)(ws + KT_OFF + (size_t)(b * NN + n) * DD + d) = st;
        } else {
            const int c = mb - 64;
#pragma unroll
            for (int rr = 0; rr < 4; rr++)
                ws[V_OFF + (size_t)(b * CH + c + rr) * NN + n] = f2bf(acc[t][rr] + bv[c + rr]);
        }
    }
}

// ---------------------------------------------------------------------------
// Kernel B: MFMA flash attention, no-max softmax (logits bounded ~|4|, exp is
// fp32-safe), j split across 2 wave-groups, prefetched loads, single barrier.
// Block = 512 threads = 8 waves: (c-quarter 0..3) x (j-half 0..1).
// ---------------------------------------------------------------------------
__global__ __launch_bounds__(512) void attn_kernel(
    const float* __restrict__ x,
    const float* __restrict__ gamma,
    const unsigned short* __restrict__ ws,
    float* __restrict__ out)
{
    const int it   = blockIdx.x;        // 0..63, i-tile of 16
    const int b    = blockIdx.y;        // 0..7
    const int tid  = threadIdx.x;
    const int wv   = (tid >> 6) & 3;    // c-quarter
    const int jh   = tid >> 8;          // j-half
    const int lane = tid & 63;
    const int n    = lane & 15;         // col index: i
    const int q4   = lane >> 4;
    const int i0   = it * 16;
    const int cb   = wv * 64;

    __shared__ float accL[4 * 16 * 64];  // 16 KB: [wv][reg][lane]
    __shared__ float lL[16];

    const unsigned short* qT = ws + QT_OFF + (size_t)b * NN * DD;
    const unsigned short* kT = ws + KT_OFF + (size_t)b * NN * DD + (size_t)jh * 512 * DD;
    const unsigned short* vp = ws + V_OFF  + (size_t)b * CH * NN + (size_t)jh * 512;

    const bf16x8 qf = *(const bf16x8*)(qT + (size_t)(i0 + n) * DD + q4 * 8);

    f32x4 acc[4];
#pragma unroll
    for (int t = 0; t < 4; t++) acc[t] = (f32x4){0.f, 0.f, 0.f, 0.f};
    float lsum = 0.f;

    // prefetch chunk 0
    bf16x8 ka0 = *(const bf16x8*)(kT + (size_t)(n) * DD + q4 * 8);
    bf16x8 ka1 = *(const bf16x8*)(kT + (size_t)(16 + n) * DD + q4 * 8);
    bf16x8 va[4];
#pragma unroll
    for (int t = 0; t < 4; t++)
        va[t] = *(const bf16x8*)(vp + (size_t)(cb + t * 16 + n) * NN + q4 * 8);

    const int qh2 = (q4 & 1) * 2;

#pragma unroll 4
    for (int ch = 0; ch < 16; ch++) {
        const bf16x8 ka0c = ka0, ka1c = ka1;
        bf16x8 vac[4];
#pragma unroll
        for (int t = 0; t < 4; t++) vac[t] = va[t];

        // prefetch next chunk (last iter over-reads inside ws — harmless)
        {
            const int j0 = (ch + 1) * 32;
            ka0 = *(const bf16x8*)(kT + (size_t)(j0 + n) * DD + q4 * 8);
            ka1 = *(const bf16x8*)(kT + (size_t)(j0 + 16 + n) * DD + q4 * 8);
#pragma unroll
            for (int t = 0; t < 4; t++)
                va[t] = *(const bf16x8*)(vp + (size_t)(cb + t * 16 + n) * NN + j0 + q4 * 8);
        }

        const f32x4 z = {0.f, 0.f, 0.f, 0.f};
        f32x4 s0 = __builtin_amdgcn_mfma_f32_16x16x32_bf16(ka0c, qf, z, 0, 0, 0);
        f32x4 s1 = __builtin_amdgcn_mfma_f32_16x16x32_bf16(ka1c, qf, z, 0, 0, 0);

        // no-max softmax: p = exp(s); l accumulated per-lane, reduced after loop
        float p0[4], p1[4];
#pragma unroll
        for (int r = 0; r < 4; r++) {
            p0[r] = __expf(s0[r]);
            p1[r] = __expf(s1[r]);
            lsum += p0[r] + p1[r];
        }

        // P (C-layout) -> B-operand via bpermute of packed bf16 pairs
        unsigned int pk0[2] = { packbf2(p0[0], p0[1]), packbf2(p0[2], p0[3]) };
        unsigned int pk1[2] = { packbf2(p1[0], p1[1]), packbf2(p1[2], p1[3]) };
        union { unsigned int u[4]; bf16x8 v; } pf;
#pragma unroll
        for (int t = 0; t < 4; t++) {
            const int src = (qh2 + (t >> 1)) * 16 + n;
            const unsigned int lo = (unsigned int)__shfl((int)pk0[t & 1], src, 64);
            const unsigned int hi = (unsigned int)__shfl((int)pk1[t & 1], src, 64);
            pf.u[t] = (q4 >= 2) ? hi : lo;
        }

#pragma unroll
        for (int t = 0; t < 4; t++)
            acc[t] = __builtin_amdgcn_mfma_f32_16x16x32_bf16(vac[t], pf.v, acc[t], 0, 0, 0);
    }

    // reduce l over quads (each lane ends with l for its column i, this j-half)
    lsum += __shfl_xor(lsum, 16, 64);
    lsum += __shfl_xor(lsum, 32, 64);

    if (jh == 1) {
#pragma unroll
        for (int t = 0; t < 4; t++)
#pragma unroll
            for (int r = 0; r < 4; r++)
                accL[(wv * 16 + t * 4 + r) * 64 + lane] = acc[t][r];
        if (wv == 0 && lane < 16) lL[lane] = lsum;
    }
    __syncthreads();

    if (jh == 0) {
        const float ltot = lsum + lL[n];
        const float rl = gamma[0] / ltot;
#pragma unroll
        for (int t = 0; t < 4; t++) {
#pragma unroll
            for (int r = 0; r < 4; r++) {
                const float a = acc[t][r] + accL[(wv * 16 + t * 4 + r) * 64 + lane];
                const int c = cb + t * 16 + q4 * 4 + r;
                const size_t idx = (size_t)(b * CH + c) * NN + i0 + n;
                out[idx] = a * rl + x[idx];
            }
        }
    }
}

extern "C" void kernel_launch(void* const* d_in, const int* in_sizes, int n_in,
                              void* d_out, int out_size, void* d_ws, size_t ws_size,
                              hipStream_t stream) {
    (void)in_sizes; (void)n_in; (void)out_size; (void)ws_size;
    const float* x     = (const float*)d_in[0];
    const float* Wq    = (const float*)d_in[1];
    const float* bq    = (const float*)d_in[2];
    const float* Wk    = (const float*)d_in[3];
    const float* bk    = (const float*)d_in[4];
    const float* Wv    = (const float*)d_in[5];
    const float* bv    = (const float*)d_in[6];
    const float* Wr    = (const float*)d_in[7];
    // d_in[8] = br: j-constant logit shift -> softmax-invariant, dropped.
    const float* gamma = (const float*)d_in[9];
    float* out = (float*)d_out;
    unsigned short* ws = (unsigned short*)d_ws;

    proj_kernel<<<dim3(64, 8), 256, 0, stream>>>(x, Wq, bq, Wk, bk, Wv, bv, Wr, ws);
    attn_kernel<<<dim3(64, 8), 512, 0, stream>>>(x, gamma, ws, out);
}

// Round 4
// 119.477 us; speedup vs baseline: 2.5533x; 1.1677x over previous
//
#include <hip/hip_runtime.h>
#include <hip/hip_bf16.h>

#define BATCH 8
#define CH    256
#define NN    1024
#define DD    32

// ws layout (bf16 shorts):
//   qT [b][i][d]   (scale folded)            512 KB
//   kT [b][j][d]   (rp + bias folded)        512 KB
//   v2 [b][jt=32][ct=16][lane=64][jj=8]      4 MB   (MFMA A-fragment-ready:
//        element (c,j): jt=j>>5, ct=c>>4, lane=((j>>3)&3)*16+(c&15), jj=j&7)
#define QT_OFF 0
#define KT_OFF (BATCH * NN * DD)
#define V_OFF  (2 * BATCH * NN * DD)
#define V2_B   (NN * CH)               // shorts per batch in v2 (262144)

#define SCALE 0.17677669529663687f     // 1/sqrt(32)
#define INV31 (1.0f / 31.0f)

typedef __attribute__((ext_vector_type(4))) float f32x4;
typedef __attribute__((ext_vector_type(8))) short bf16x8;

__device__ __forceinline__ unsigned int packbf2(float lo, float hi) {
    __hip_bfloat162 h = __float22bfloat162_rn(make_float2(lo, hi));
    union { __hip_bfloat162 h; unsigned int u; } cv; cv.h = h;
    return cv.u;
}
__device__ __forceinline__ unsigned short f2bf(float x) {
    union { float f; unsigned int u; } v; v.f = x;
    return (unsigned short)((v.u + 0x7FFFu + ((v.u >> 16) & 1u)) >> 16);
}

// ---------------------------------------------------------------------------
// Kernel P: MFMA projection, no LDS, no barriers.
// Block = 320m x 16n for one batch; 4 waves, each 5 m-frags (80 m) x 16 n.
// v epilogue writes the fragment-ready v2 layout (2B scattered stores — proj
// is far off the critical path).
// ---------------------------------------------------------------------------
__global__ __launch_bounds__(256) void proj_kernel(
    const float* __restrict__ x,
    const float* __restrict__ Wq, const float* __restrict__ bq,
    const float* __restrict__ Wk, const float* __restrict__ bk,
    const float* __restrict__ Wv, const float* __restrict__ bv,
    const float* __restrict__ Wr,
    unsigned short* __restrict__ ws)
{
    const int nt   = blockIdx.x;   // 0..63
    const int b    = blockIdx.y;   // 0..7
    const int tid  = threadIdx.x;
    const int wv   = tid >> 6;     // 0..3 (m-group)
    const int lane = tid & 63;
    const int n16  = lane & 15;
    const int q4   = lane >> 4;
    const int n    = nt * 16 + n16;

    f32x4 acc[5];
#pragma unroll
    for (int t = 0; t < 5; t++) acc[t] = (f32x4){0.f, 0.f, 0.f, 0.f};

    const float* wrow[5];
#pragma unroll
    for (int t = 0; t < 5; t++) {
        const int m = (wv * 5 + t) * 16 + n16;
        wrow[t] = (m < 32) ? (Wq + m * CH)
                : (m < 64) ? (Wk + (m - 32) * CH)
                           : (Wv + (m - 64) * CH);
    }

    for (int c0 = 0; c0 < CH; c0 += 32) {
        const int kofs = c0 + q4 * 8;
        float bx[8];
#pragma unroll
        for (int jj = 0; jj < 8; jj++)
            bx[jj] = x[(size_t)(b * CH + kofs + jj) * NN + n];
        union { unsigned int u[4]; bf16x8 v; } bf;
#pragma unroll
        for (int p = 0; p < 4; p++) bf.u[p] = packbf2(bx[2 * p], bx[2 * p + 1]);

#pragma unroll
        for (int t = 0; t < 5; t++) {
            const float* wp = wrow[t] + kofs;
            const float4 a0 = *(const float4*)(wp);
            const float4 a1 = *(const float4*)(wp + 4);
            union { unsigned int u[4]; bf16x8 v; } af;
            af.u[0] = packbf2(a0.x, a0.y); af.u[1] = packbf2(a0.z, a0.w);
            af.u[2] = packbf2(a1.x, a1.y); af.u[3] = packbf2(a1.z, a1.w);
            acc[t] = __builtin_amdgcn_mfma_f32_16x16x32_bf16(af.v, bf.v, acc[t], 0, 0, 0);
        }
    }

    // epilogue: C rows m = mf*16 + q4*4 + r, col n
    const int jt  = n >> 5;          // v2 indices for this thread's j (= n)
    const int q4p = (n >> 3) & 3;
    const int jj  = n & 7;
#pragma unroll
    for (int t = 0; t < 5; t++) {
        const int mf = wv * 5 + t;
        const int mb = mf * 16 + q4 * 4;
        if (mb < 32) {
            const float r0 = (acc[t][0] + bq[mb + 0]) * SCALE;
            const float r1 = (acc[t][1] + bq[mb + 1]) * SCALE;
            const float r2 = (acc[t][2] + bq[mb + 2]) * SCALE;
            const float r3 = (acc[t][3] + bq[mb + 3]) * SCALE;
            uint2 st = { packbf2(r0, r1), packbf2(r2, r3) };
            *(uint2*)(ws + QT_OFF + (size_t)(b * NN + n) * DD + mb) = st;
        } else if (mb < 64) {
            const int d = mb - 32;
            const float An = (float)(n >> 5) * INV31;
            const float Bn = (float)(n & 31) * INV31;
            float r[4];
#pragma unroll
            for (int rr = 0; rr < 4; rr++)
                r[rr] = acc[t][rr] + bk[d + rr] - An * Wr[2 * (d + rr)] - Bn * Wr[2 * (d + rr) + 1];
            uint2 st = { packbf2(r[0], r[1]), packbf2(r[2], r[3]) };
            *(uint2*)(ws + KT_OFF + (size_t)(b * NN + n) * DD + d) = st;
        } else {
            const int c = mb - 64;
#pragma unroll
            for (int rr = 0; rr < 4; rr++) {
                const int cc = c + rr;
                const size_t off = V_OFF + (size_t)b * V2_B
                                 + (size_t)jt * 8192 + (size_t)(cc >> 4) * 512
                                 + (size_t)(q4p * 16 + (cc & 15)) * 8 + jj;
                ws[off] = f2bf(acc[t][rr] + bv[cc]);
            }
        }
    }
}

// ---------------------------------------------------------------------------
// Kernel B: MFMA flash attention, no-max softmax (logits bounded, exp fp32-
// safe), j split across 2 wave-groups, prefetch, single barrier.
// Block = 512 threads = 8 waves: (c-quarter 0..3) x (j-half 0..1).
// All global loads are wave-contiguous (v via the v2 fragment layout).
// ---------------------------------------------------------------------------
__global__ __launch_bounds__(512) void attn_kernel(
    const float* __restrict__ x,
    const float* __restrict__ gamma,
    const unsigned short* __restrict__ ws,
    float* __restrict__ out)
{
    const int it   = blockIdx.x;        // 0..63, i-tile of 16
    const int b    = blockIdx.y;        // 0..7
    const int tid  = threadIdx.x;
    const int wv   = (tid >> 6) & 3;    // c-quarter
    const int jh   = tid >> 8;          // j-half
    const int lane = tid & 63;
    const int n    = lane & 15;         // col index: i
    const int q4   = lane >> 4;
    const int i0   = it * 16;
    const int cb   = wv * 64;

    __shared__ float accL[4 * 16 * 64];  // 16 KB: [wv][reg][lane]
    __shared__ float lL[16];

    const unsigned short* qT = ws + QT_OFF + (size_t)b * NN * DD;
    const unsigned short* kT = ws + KT_OFF + (size_t)b * NN * DD + (size_t)jh * 512 * DD;
    // v2 base for this wave: batch + j-half (16 jt tiles) + c-quarter (4 ct) + lane
    const unsigned short* vb = ws + V_OFF + (size_t)b * V2_B
                             + (size_t)jh * 16 * 8192 + (size_t)wv * 4 * 512
                             + (size_t)lane * 8;

    const bf16x8 qf = *(const bf16x8*)(qT + (size_t)(i0 + n) * DD + q4 * 8);

    f32x4 acc[4];
#pragma unroll
    for (int t = 0; t < 4; t++) acc[t] = (f32x4){0.f, 0.f, 0.f, 0.f};
    float lsum = 0.f;

    // prefetch chunk 0
    bf16x8 ka0 = *(const bf16x8*)(kT + (size_t)(n) * DD + q4 * 8);
    bf16x8 ka1 = *(const bf16x8*)(kT + (size_t)(16 + n) * DD + q4 * 8);
    bf16x8 va[4];
#pragma unroll
    for (int t = 0; t < 4; t++)
        va[t] = *(const bf16x8*)(vb + t * 512);

    const int qh2 = (q4 & 1) * 2;

#pragma unroll 4
    for (int ch = 0; ch < 16; ch++) {
        const bf16x8 ka0c = ka0, ka1c = ka1;
        bf16x8 vac[4];
#pragma unroll
        for (int t = 0; t < 4; t++) vac[t] = va[t];

        // prefetch next chunk (last iter over-reads inside ws — harmless)
        {
            const int j0 = (ch + 1) * 32;
            ka0 = *(const bf16x8*)(kT + (size_t)(j0 + n) * DD + q4 * 8);
            ka1 = *(const bf16x8*)(kT + (size_t)(j0 + 16 + n) * DD + q4 * 8);
#pragma unroll
            for (int t = 0; t < 4; t++)
                va[t] = *(const bf16x8*)(vb + (ch + 1) * 8192 + t * 512);
        }

        const f32x4 z = {0.f, 0.f, 0.f, 0.f};
        f32x4 s0 = __builtin_amdgcn_mfma_f32_16x16x32_bf16(ka0c, qf, z, 0, 0, 0);
        f32x4 s1 = __builtin_amdgcn_mfma_f32_16x16x32_bf16(ka1c, qf, z, 0, 0, 0);

        float p0[4], p1[4];
#pragma unroll
        for (int r = 0; r < 4; r++) {
            p0[r] = __expf(s0[r]);
            p1[r] = __expf(s1[r]);
            lsum += p0[r] + p1[r];
        }

        // P (C-layout) -> B-operand via shuffles of packed bf16 pairs
        unsigned int pk0[2] = { packbf2(p0[0], p0[1]), packbf2(p0[2], p0[3]) };
        unsigned int pk1[2] = { packbf2(p1[0], p1[1]), packbf2(p1[2], p1[3]) };
        union { unsigned int u[4]; bf16x8 v; } pf;
#pragma unroll
        for (int t = 0; t < 4; t++) {
            const int src = (qh2 + (t >> 1)) * 16 + n;
            const unsigned int lo = (unsigned int)__shfl((int)pk0[t & 1], src, 64);
            const unsigned int hi = (unsigned int)__shfl((int)pk1[t & 1], src, 64);
            pf.u[t] = (q4 >= 2) ? hi : lo;
        }

#pragma unroll
        for (int t = 0; t < 4; t++)
            acc[t] = __builtin_amdgcn_mfma_f32_16x16x32_bf16(vac[t], pf.v, acc[t], 0, 0, 0);
    }

    lsum += __shfl_xor(lsum, 16, 64);
    lsum += __shfl_xor(lsum, 32, 64);

    if (jh == 1) {
#pragma unroll
        for (int t = 0; t < 4; t++)
#pragma unroll
            for (int r = 0; r < 4; r++)
                accL[(wv * 16 + t * 4 + r) * 64 + lane] = acc[t][r];
        if (wv == 0 && lane < 16) lL[lane] = lsum;
    }
    __syncthreads();

    if (jh == 0) {
        const float ltot = lsum + lL[n];
        const float rl = gamma[0] / ltot;
#pragma unroll
        for (int t = 0; t < 4; t++) {
#pragma unroll
            for (int r = 0; r < 4; r++) {
                const float a = acc[t][r] + accL[(wv * 16 + t * 4 + r) * 64 + lane];
                const int c = cb + t * 16 + q4 * 4 + r;
                const size_t idx = (size_t)(b * CH + c) * NN + i0 + n;
                out[idx] = a * rl + x[idx];
            }
        }
    }
}

extern "C" void kernel_launch(void* const* d_in, const int* in_sizes, int n_in,
                              void* d_out, int out_size, void* d_ws, size_t ws_size,
                              hipStream_t stream) {
    (void)in_sizes; (void)n_in; (void)out_size; (void)ws_size;
    const float* x     = (const float*)d_in[0];
    const float* Wq    = (const float*)d_in[1];
    const float* bq    = (const float*)d_in[2];
    const float* Wk    = (const float*)d_in[3];
    const float* bk    = (const float*)d_in[4];
    const float* Wv    = (const float*)d_in[5];
    const float* bv    = (const float*)d_in[6];
    const float* Wr    = (const float*)d_in[7];
    // d_in[8] = br: j-constant logit shift -> softmax-invariant, dropped.
    const float* gamma = (const float*)d_in[9];
    float* out = (float*)d_out;
    unsigned short* ws = (unsigned short*)d_ws;

    proj_kernel<<<dim3(64, 8), 256, 0, stream>>>(x, Wq, bq, Wk, bk, Wv, bv, Wr, ws);
    attn_kernel<<<dim3(64, 8), 512, 0, stream>>>(x, gamma, ws, out);
}

// Round 5
// 117.660 us; speedup vs baseline: 2.5927x; 1.0154x over previous
//
#include <hip/hip_runtime.h>
#include <hip/hip_bf16.h>

#define BATCH 8
#define CH    256
#define NN    1024
#define DD    32

// ws layout (bf16 shorts):
//   qT [b][i][d]   (scale*log2e folded)      512 KB
//   kT [b][j][d]   (rp + bias folded)        512 KB
//   v2 [b][jt=32][ct=16][lane=64][jj=8]      4 MB   (MFMA A-fragment-ready:
//        element (c,j): jt=j>>5, ct=c>>4, lane=((j>>3)&3)*16+(c&15), jj=j&7)
#define QT_OFF 0
#define KT_OFF (BATCH * NN * DD)
#define V_OFF  (2 * BATCH * NN * DD)
#define V2_B   (NN * CH)               // shorts per batch in v2 (262144)

// 1/sqrt(32) * log2(e): softmax via exp2 (v_exp_f32 is native 2^x)
#define SCALE_Q (0.17677669529663687f * 1.4426950408889634f)
#define INV31 (1.0f / 31.0f)

typedef __attribute__((ext_vector_type(4))) float f32x4;
typedef __attribute__((ext_vector_type(8))) short bf16x8;

__device__ __forceinline__ unsigned int packbf2(float lo, float hi) {
    __hip_bfloat162 h = __float22bfloat162_rn(make_float2(lo, hi));
    union { __hip_bfloat162 h; unsigned int u; } cv; cv.h = h;
    return cv.u;
}
__device__ __forceinline__ unsigned short f2bf(float x) {
    union { float f; unsigned int u; } v; v.f = x;
    return (unsigned short)((v.u + 0x7FFFu + ((v.u >> 16) & 1u)) >> 16);
}

// ---------------------------------------------------------------------------
// Kernel P: MFMA projection, no LDS, no barriers. (unchanged except SCALE_Q)
// ---------------------------------------------------------------------------
__global__ __launch_bounds__(256) void proj_kernel(
    const float* __restrict__ x,
    const float* __restrict__ Wq, const float* __restrict__ bq,
    const float* __restrict__ Wk, const float* __restrict__ bk,
    const float* __restrict__ Wv, const float* __restrict__ bv,
    const float* __restrict__ Wr,
    unsigned short* __restrict__ ws)
{
    const int nt   = blockIdx.x;   // 0..63
    const int b    = blockIdx.y;   // 0..7
    const int tid  = threadIdx.x;
    const int wv   = tid >> 6;     // 0..3 (m-group)
    const int lane = tid & 63;
    const int n16  = lane & 15;
    const int q4   = lane >> 4;
    const int n    = nt * 16 + n16;

    f32x4 acc[5];
#pragma unroll
    for (int t = 0; t < 5; t++) acc[t] = (f32x4){0.f, 0.f, 0.f, 0.f};

    const float* wrow[5];
#pragma unroll
    for (int t = 0; t < 5; t++) {
        const int m = (wv * 5 + t) * 16 + n16;
        wrow[t] = (m < 32) ? (Wq + m * CH)
                : (m < 64) ? (Wk + (m - 32) * CH)
                           : (Wv + (m - 64) * CH);
    }

    for (int c0 = 0; c0 < CH; c0 += 32) {
        const int kofs = c0 + q4 * 8;
        float bx[8];
#pragma unroll
        for (int jj = 0; jj < 8; jj++)
            bx[jj] = x[(size_t)(b * CH + kofs + jj) * NN + n];
        union { unsigned int u[4]; bf16x8 v; } bf;
#pragma unroll
        for (int p = 0; p < 4; p++) bf.u[p] = packbf2(bx[2 * p], bx[2 * p + 1]);

#pragma unroll
        for (int t = 0; t < 5; t++) {
            const float* wp = wrow[t] + kofs;
            const float4 a0 = *(const float4*)(wp);
            const float4 a1 = *(const float4*)(wp + 4);
            union { unsigned int u[4]; bf16x8 v; } af;
            af.u[0] = packbf2(a0.x, a0.y); af.u[1] = packbf2(a0.z, a0.w);
            af.u[2] = packbf2(a1.x, a1.y); af.u[3] = packbf2(a1.z, a1.w);
            acc[t] = __builtin_amdgcn_mfma_f32_16x16x32_bf16(af.v, bf.v, acc[t], 0, 0, 0);
        }
    }

    const int jt  = n >> 5;
    const int q4p = (n >> 3) & 3;
    const int jj  = n & 7;
#pragma unroll
    for (int t = 0; t < 5; t++) {
        const int mf = wv * 5 + t;
        const int mb = mf * 16 + q4 * 4;
        if (mb < 32) {
            const float r0 = (acc[t][0] + bq[mb + 0]) * SCALE_Q;
            const float r1 = (acc[t][1] + bq[mb + 1]) * SCALE_Q;
            const float r2 = (acc[t][2] + bq[mb + 2]) * SCALE_Q;
            const float r3 = (acc[t][3] + bq[mb + 3]) * SCALE_Q;
            uint2 st = { packbf2(r0, r1), packbf2(r2, r3) };
            *(uint2*)(ws + QT_OFF + (size_t)(b * NN + n) * DD + mb) = st;
        } else if (mb < 64) {
            const int d = mb - 32;
            const float An = (float)(n >> 5) * INV31;
            const float Bn = (float)(n & 31) * INV31;
            float r[4];
#pragma unroll
            for (int rr = 0; rr < 4; rr++)
                r[rr] = acc[t][rr] + bk[d + rr] - An * Wr[2 * (d + rr)] - Bn * Wr[2 * (d + rr) + 1];
            uint2 st = { packbf2(r[0], r[1]), packbf2(r[2], r[3]) };
            *(uint2*)(ws + KT_OFF + (size_t)(b * NN + n) * DD + d) = st;
        } else {
            const int c = mb - 64;
#pragma unroll
            for (int rr = 0; rr < 4; rr++) {
                const int cc = c + rr;
                const size_t off = V_OFF + (size_t)b * V2_B
                                 + (size_t)jt * 8192 + (size_t)(cc >> 4) * 512
                                 + (size_t)(q4p * 16 + (cc & 15)) * 8 + jj;
                ws[off] = f2bf(acc[t][rr] + bv[cc]);
            }
        }
    }
}

// ---------------------------------------------------------------------------
// Kernel B: MFMA flash attention, 2 i-tiles per block (32 queries), no-max
// softmax via exp2, j-split 2, prefetch, single barrier.
// Block = 512 threads = 8 waves: (c-quarter 0..3) x (j-half 0..1).
// 256 blocks (1/CU). V stream amortized over 2 i-tiles -> half the traffic.
// ---------------------------------------------------------------------------
__global__ __launch_bounds__(512) void attn_kernel(
    const float* __restrict__ x,
    const float* __restrict__ gamma,
    const unsigned short* __restrict__ ws,
    float* __restrict__ out)
{
    const int it   = blockIdx.x;        // 0..31, i-group of 32
    const int b    = blockIdx.y;        // 0..7
    const int tid  = threadIdx.x;
    const int wv   = (tid >> 6) & 3;    // c-quarter
    const int jh   = tid >> 8;          // j-half
    const int lane = tid & 63;
    const int n    = lane & 15;         // col index: i (within tile)
    const int q4   = lane >> 4;
    const int i0   = it * 32;
    const int cb   = wv * 64;

    __shared__ float accL[4 * 32 * 64];  // 32 KB: [wv][tile*16+reg][lane]
    __shared__ float lL[32];

    const unsigned short* qT = ws + QT_OFF + (size_t)b * NN * DD;
    const unsigned short* kT = ws + KT_OFF + (size_t)b * NN * DD + (size_t)jh * 512 * DD;
    const unsigned short* vb = ws + V_OFF + (size_t)b * V2_B
                             + (size_t)jh * 16 * 8192 + (size_t)wv * 4 * 512
                             + (size_t)lane * 8;

    const bf16x8 qf0 = *(const bf16x8*)(qT + (size_t)(i0 + n) * DD + q4 * 8);
    const bf16x8 qf1 = *(const bf16x8*)(qT + (size_t)(i0 + 16 + n) * DD + q4 * 8);

    f32x4 acc0[4], acc1[4];
#pragma unroll
    for (int t = 0; t < 4; t++) {
        acc0[t] = (f32x4){0.f, 0.f, 0.f, 0.f};
        acc1[t] = (f32x4){0.f, 0.f, 0.f, 0.f};
    }
    float lsum0 = 0.f, lsum1 = 0.f;

    // prefetch chunk 0
    bf16x8 ka0 = *(const bf16x8*)(kT + (size_t)(n) * DD + q4 * 8);
    bf16x8 ka1 = *(const bf16x8*)(kT + (size_t)(16 + n) * DD + q4 * 8);
    bf16x8 va[4];
#pragma unroll
    for (int t = 0; t < 4; t++)
        va[t] = *(const bf16x8*)(vb + t * 512);

    const int qh2 = (q4 & 1) * 2;
    int src[4];
#pragma unroll
    for (int t = 0; t < 4; t++) src[t] = (qh2 + (t >> 1)) * 16 + n;

#pragma unroll 4
    for (int ch = 0; ch < 16; ch++) {
        const bf16x8 ka0c = ka0, ka1c = ka1;
        bf16x8 vac[4];
#pragma unroll
        for (int t = 0; t < 4; t++) vac[t] = va[t];

        // prefetch next chunk (last iter over-reads inside ws — harmless)
        {
            const int j0 = (ch + 1) * 32;
            ka0 = *(const bf16x8*)(kT + (size_t)(j0 + n) * DD + q4 * 8);
            ka1 = *(const bf16x8*)(kT + (size_t)(j0 + 16 + n) * DD + q4 * 8);
#pragma unroll
            for (int t = 0; t < 4; t++)
                va[t] = *(const bf16x8*)(vb + (ch + 1) * 8192 + t * 512);
        }

        const f32x4 z = {0.f, 0.f, 0.f, 0.f};
        f32x4 s0a = __builtin_amdgcn_mfma_f32_16x16x32_bf16(ka0c, qf0, z, 0, 0, 0);
        f32x4 s1a = __builtin_amdgcn_mfma_f32_16x16x32_bf16(ka1c, qf0, z, 0, 0, 0);
        f32x4 s0b = __builtin_amdgcn_mfma_f32_16x16x32_bf16(ka0c, qf1, z, 0, 0, 0);
        f32x4 s1b = __builtin_amdgcn_mfma_f32_16x16x32_bf16(ka1c, qf1, z, 0, 0, 0);

        float p0a[4], p1a[4], p0b[4], p1b[4];
#pragma unroll
        for (int r = 0; r < 4; r++) {
            p0a[r] = exp2f(s0a[r]);
            p1a[r] = exp2f(s1a[r]);
            p0b[r] = exp2f(s0b[r]);
            p1b[r] = exp2f(s1b[r]);
            lsum0 += p0a[r] + p1a[r];
            lsum1 += p0b[r] + p1b[r];
        }

        // P (C-layout) -> B-operand via shuffles of packed bf16 pairs
        unsigned int pk0a[2] = { packbf2(p0a[0], p0a[1]), packbf2(p0a[2], p0a[3]) };
        unsigned int pk1a[2] = { packbf2(p1a[0], p1a[1]), packbf2(p1a[2], p1a[3]) };
        unsigned int pk0b[2] = { packbf2(p0b[0], p0b[1]), packbf2(p0b[2], p0b[3]) };
        unsigned int pk1b[2] = { packbf2(p1b[0], p1b[1]), packbf2(p1b[2], p1b[3]) };
        union { unsigned int u[4]; bf16x8 v; } pfa, pfb;
#pragma unroll
        for (int t = 0; t < 4; t++) {
            const unsigned int loa = (unsigned int)__shfl((int)pk0a[t & 1], src[t], 64);
            const unsigned int hia = (unsigned int)__shfl((int)pk1a[t & 1], src[t], 64);
            const unsigned int lob = (unsigned int)__shfl((int)pk0b[t & 1], src[t], 64);
            const unsigned int hib = (unsigned int)__shfl((int)pk1b[t & 1], src[t], 64);
            pfa.u[t] = (q4 >= 2) ? hia : loa;
            pfb.u[t] = (q4 >= 2) ? hib : lob;
        }

#pragma unroll
        for (int t = 0; t < 4; t++) {
            acc0[t] = __builtin_amdgcn_mfma_f32_16x16x32_bf16(vac[t], pfa.v, acc0[t], 0, 0, 0);
            acc1[t] = __builtin_amdgcn_mfma_f32_16x16x32_bf16(vac[t], pfb.v, acc1[t], 0, 0, 0);
        }
    }

    lsum0 += __shfl_xor(lsum0, 16, 64);
    lsum0 += __shfl_xor(lsum0, 32, 64);
    lsum1 += __shfl_xor(lsum1, 16, 64);
    lsum1 += __shfl_xor(lsum1, 32, 64);

    if (jh == 1) {
#pragma unroll
        for (int t = 0; t < 4; t++)
#pragma unroll
            for (int r = 0; r < 4; r++) {
                accL[(wv * 32 + t * 4 + r) * 64 + lane]      = acc0[t][r];
                accL[(wv * 32 + 16 + t * 4 + r) * 64 + lane] = acc1[t][r];
            }
        if (wv == 0 && lane < 16) lL[lane] = lsum0;
        if (wv == 1 && lane < 16) lL[16 + lane] = lsum1;
    }
    __syncthreads();

    if (jh == 0) {
        const float g = gamma[0];
        const float rl0 = g / (lsum0 + lL[n]);
        const float rl1 = g / (lsum1 + lL[16 + n]);
#pragma unroll
        for (int t = 0; t < 4; t++) {
#pragma unroll
            for (int r = 0; r < 4; r++) {
                const int c = cb + t * 16 + q4 * 4 + r;
                const size_t base = (size_t)(b * CH + c) * NN + i0 + n;
                const float a0 = acc0[t][r] + accL[(wv * 32 + t * 4 + r) * 64 + lane];
                const float a1 = acc1[t][r] + accL[(wv * 32 + 16 + t * 4 + r) * 64 + lane];
                out[base]      = a0 * rl0 + x[base];
                out[base + 16] = a1 * rl1 + x[base + 16];
            }
        }
    }
}

extern "C" void kernel_launch(void* const* d_in, const int* in_sizes, int n_in,
                              void* d_out, int out_size, void* d_ws, size_t ws_size,
                              hipStream_t stream) {
    (void)in_sizes; (void)n_in; (void)out_size; (void)ws_size;
    const float* x     = (const float*)d_in[0];
    const float* Wq    = (const float*)d_in[1];
    const float* bq    = (const float*)d_in[2];
    const float* Wk    = (const float*)d_in[3];
    const float* bk    = (const float*)d_in[4];
    const float* Wv    = (const float*)d_in[5];
    const float* bv    = (const float*)d_in[6];
    const float* Wr    = (const float*)d_in[7];
    // d_in[8] = br: j-constant logit shift -> softmax-invariant, dropped.
    const float* gamma = (const float*)d_in[9];
    float* out = (float*)d_out;
    unsigned short* ws = (unsigned short*)d_ws;

    proj_kernel<<<dim3(64, 8), 256, 0, stream>>>(x, Wq, bq, Wk, bk, Wv, bv, Wr, ws);
    attn_kernel<<<dim3(32, 8), 512, 0, stream>>>(x, gamma, ws, out);
}

// Round 6
// 114.414 us; speedup vs baseline: 2.6663x; 1.0284x over previous
//
#include <hip/hip_runtime.h>
#include <hip/hip_bf16.h>

#define BATCH 8
#define CH    256
#define NN    1024
#define DD    32

// ws layout (bf16 shorts):
//   qT [b][i][d]   (scale*log2e folded)      512 KB
//   kT [b][j][d]   (rp + bias folded)        512 KB
//   v2 [b][jt=32][ct=16][lane=64][jj=8]      4 MB   (MFMA A-frag-ready)
//   wf [mf=20][kc=8][lane=64][jj=8]          160 KB (W in A-frag-ready bf16)
#define QT_OFF 0
#define KT_OFF (BATCH * NN * DD)
#define V_OFF  (2 * BATCH * NN * DD)
#define V2_B   (NN * CH)                       // shorts per batch in v2
#define WF_OFF (V_OFF + BATCH * V2_B)          // 2621440

// 1/sqrt(32) * log2(e): softmax via exp2 (v_exp_f32 is native 2^x)
#define SCALE_Q (0.17677669529663687f * 1.4426950408889634f)
#define INV31 (1.0f / 31.0f)

typedef __attribute__((ext_vector_type(4))) float f32x4;
typedef __attribute__((ext_vector_type(8))) short bf16x8;

__device__ __forceinline__ unsigned int packbf2(float lo, float hi) {
    __hip_bfloat162 h = __float22bfloat162_rn(make_float2(lo, hi));
    union { __hip_bfloat162 h; unsigned int u; } cv; cv.h = h;
    return cv.u;
}
__device__ __forceinline__ unsigned short f2bf(float x) {
    union { float f; unsigned int u; } v; v.f = x;
    return (unsigned short)((v.u + 0x7FFFu + ((v.u >> 16) & 1u)) >> 16);
}

// ---------------------------------------------------------------------------
// Kernel W: repack W_all (320x256 fp32) into MFMA-A-fragment-ready bf16.
// Coalesced float4 reads (one wave = one W row), 8 B scattered writes (160 KB
// total — trivial). Element (m,k) -> wf[(m>>4)*8 + (k>>5)][((k>>3)&3)*16+(m&15)][k&7].
// ---------------------------------------------------------------------------
__global__ __launch_bounds__(256) void wrepack_kernel(
    const float* __restrict__ Wq, const float* __restrict__ Wk,
    const float* __restrict__ Wv, unsigned short* __restrict__ ws)
{
    const int gid = blockIdx.x * 256 + threadIdx.x;   // 0..20479
    const int e = gid * 4;
    const int m = e >> 8;
    const int k = e & 255;
    const float* src = (m < 32) ? (Wq + m * CH + k)
                     : (m < 64) ? (Wk + (m - 32) * CH + k)
                                : (Wv + (m - 64) * CH + k);
    const float4 w = *(const float4*)src;
    const int mf = m >> 4, kc = k >> 5;
    const int lf = ((k >> 3) & 3) * 16 + (m & 15);
    const int jj = k & 7;                              // 0 or 4
    uint2 st = { packbf2(w.x, w.y), packbf2(w.z, w.w) };
    *(uint2*)(ws + WF_OFF + ((size_t)(mf * 8 + kc) * 64 + lf) * 8 + jj) = st;
}

// ---------------------------------------------------------------------------
// Kernel P: MFMA projection. A-frags are now fragment-linear b128 loads from
// wf (no 16-line gather); B-frags from x (scalar, 4x64B per wave-load).
// ---------------------------------------------------------------------------
__global__ __launch_bounds__(256) void proj_kernel(
    const float* __restrict__ x,
    const float* __restrict__ bq, const float* __restrict__ bk,
    const float* __restrict__ bv, const float* __restrict__ Wr,
    unsigned short* __restrict__ ws)
{
    const int nt   = blockIdx.x;   // 0..63
    const int b    = blockIdx.y;   // 0..7
    const int tid  = threadIdx.x;
    const int wv   = tid >> 6;     // 0..3 (m-group)
    const int lane = tid & 63;
    const int n16  = lane & 15;
    const int q4   = lane >> 4;
    const int n    = nt * 16 + n16;

    f32x4 acc[5];
#pragma unroll
    for (int t = 0; t < 5; t++) acc[t] = (f32x4){0.f, 0.f, 0.f, 0.f};

    const unsigned short* wfl = ws + WF_OFF + (size_t)lane * 8;

    for (int kc = 0; kc < 8; kc++) {
        const int kofs = kc * 32 + q4 * 8;
        float bx[8];
#pragma unroll
        for (int jj = 0; jj < 8; jj++)
            bx[jj] = x[(size_t)(b * CH + kofs + jj) * NN + n];
        union { unsigned int u[4]; bf16x8 v; } bf;
#pragma unroll
        for (int p = 0; p < 4; p++) bf.u[p] = packbf2(bx[2 * p], bx[2 * p + 1]);

#pragma unroll
        for (int t = 0; t < 5; t++) {
            const bf16x8 af = *(const bf16x8*)(wfl + (size_t)((wv * 5 + t) * 8 + kc) * 512);
            acc[t] = __builtin_amdgcn_mfma_f32_16x16x32_bf16(af, bf.v, acc[t], 0, 0, 0);
        }
    }

    const int jt  = n >> 5;
    const int q4p = (n >> 3) & 3;
    const int jj  = n & 7;
#pragma unroll
    for (int t = 0; t < 5; t++) {
        const int mf = wv * 5 + t;
        const int mb = mf * 16 + q4 * 4;
        if (mb < 32) {
            const float r0 = (acc[t][0] + bq[mb + 0]) * SCALE_Q;
            const float r1 = (acc[t][1] + bq[mb + 1]) * SCALE_Q;
            const float r2 = (acc[t][2] + bq[mb + 2]) * SCALE_Q;
            const float r3 = (acc[t][3] + bq[mb + 3]) * SCALE_Q;
            uint2 st = { packbf2(r0, r1), packbf2(r2, r3) };
            *(uint2*)(ws + QT_OFF + (size_t)(b * NN + n) * DD + mb) = st;
        } else if (mb < 64) {
            const int d = mb - 32;
            const float An = (float)(n >> 5) * INV31;
            const float Bn = (float)(n & 31) * INV31;
            float r[4];
#pragma unroll
            for (int rr = 0; rr < 4; rr++)
                r[rr] = acc[t][rr] + bk[d + rr] - An * Wr[2 * (d + rr)] - Bn * Wr[2 * (d + rr) + 1];
            uint2 st = { packbf2(r[0], r[1]), packbf2(r[2], r[3]) };
            *(uint2*)(ws + KT_OFF + (size_t)(b * NN + n) * DD + d) = st;
        } else {
            const int c = mb - 64;
#pragma unroll
            for (int rr = 0; rr < 4; rr++) {
                const int cc = c + rr;
                const size_t off = V_OFF + (size_t)b * V2_B
                                 + (size_t)jt * 8192 + (size_t)(cc >> 4) * 512
                                 + (size_t)(q4p * 16 + (cc & 15)) * 8 + jj;
                ws[off] = f2bf(acc[t][rr] + bv[cc]);
            }
        }
    }
}

// ---------------------------------------------------------------------------
// Kernel B: MFMA flash attention, 2 i-tiles/block, no-max softmax via exp2,
// j-split 2, 2-deep prefetch, single barrier. 256 blocks x 512 threads.
// ---------------------------------------------------------------------------
__global__ __launch_bounds__(512) void attn_kernel(
    const float* __restrict__ x,
    const float* __restrict__ gamma,
    const unsigned short* __restrict__ ws,
    float* __restrict__ out)
{
    const int it   = blockIdx.x;        // 0..31, i-group of 32
    const int b    = blockIdx.y;        // 0..7
    const int tid  = threadIdx.x;
    const int wv   = (tid >> 6) & 3;    // c-quarter
    const int jh   = tid >> 8;          // j-half
    const int lane = tid & 63;
    const int n    = lane & 15;         // col index: i (within tile)
    const int q4   = lane >> 4;
    const int i0   = it * 32;
    const int cb   = wv * 64;

    __shared__ float accL[4 * 32 * 64];  // 32 KB
    __shared__ float lL[32];

    const unsigned short* qT = ws + QT_OFF + (size_t)b * NN * DD;
    const unsigned short* kT = ws + KT_OFF + (size_t)b * NN * DD + (size_t)jh * 512 * DD;
    const unsigned short* vb = ws + V_OFF + (size_t)b * V2_B
                             + (size_t)jh * 16 * 8192 + (size_t)wv * 4 * 512
                             + (size_t)lane * 8;

    const bf16x8 qf0 = *(const bf16x8*)(qT + (size_t)(i0 + n) * DD + q4 * 8);
    const bf16x8 qf1 = *(const bf16x8*)(qT + (size_t)(i0 + 16 + n) * DD + q4 * 8);

    f32x4 acc0[4], acc1[4];
#pragma unroll
    for (int t = 0; t < 4; t++) {
        acc0[t] = (f32x4){0.f, 0.f, 0.f, 0.f};
        acc1[t] = (f32x4){0.f, 0.f, 0.f, 0.f};
    }
    float lsum0 = 0.f, lsum1 = 0.f;

    // 2-deep prefetch pipeline (stages 0/1); over-reads land inside ws.
    bf16x8 kaS[2][2];
    bf16x8 vaS[2][4];
#pragma unroll
    for (int s = 0; s < 2; s++) {
        const int j0 = s * 32;
        kaS[s][0] = *(const bf16x8*)(kT + (size_t)(j0 + n) * DD + q4 * 8);
        kaS[s][1] = *(const bf16x8*)(kT + (size_t)(j0 + 16 + n) * DD + q4 * 8);
#pragma unroll
        for (int t = 0; t < 4; t++)
            vaS[s][t] = *(const bf16x8*)(vb + s * 8192 + t * 512);
    }

    const int qh2 = (q4 & 1) * 2;
    int src[4];
#pragma unroll
    for (int t = 0; t < 4; t++) src[t] = (qh2 + (t >> 1)) * 16 + n;

#pragma unroll 4
    for (int ch = 0; ch < 16; ch++) {
        const int st = ch & 1;
        const bf16x8 ka0c = kaS[st][0], ka1c = kaS[st][1];
        bf16x8 vac[4];
#pragma unroll
        for (int t = 0; t < 4; t++) vac[t] = vaS[st][t];

        // prefetch ch+2 into this stage
        {
            const int j0 = (ch + 2) * 32;
            kaS[st][0] = *(const bf16x8*)(kT + (size_t)(j0 + n) * DD + q4 * 8);
            kaS[st][1] = *(const bf16x8*)(kT + (size_t)(j0 + 16 + n) * DD + q4 * 8);
#pragma unroll
            for (int t = 0; t < 4; t++)
                vaS[st][t] = *(const bf16x8*)(vb + (ch + 2) * 8192 + t * 512);
        }

        const f32x4 z = {0.f, 0.f, 0.f, 0.f};
        f32x4 s0a = __builtin_amdgcn_mfma_f32_16x16x32_bf16(ka0c, qf0, z, 0, 0, 0);
        f32x4 s1a = __builtin_amdgcn_mfma_f32_16x16x32_bf16(ka1c, qf0, z, 0, 0, 0);
        f32x4 s0b = __builtin_amdgcn_mfma_f32_16x16x32_bf16(ka0c, qf1, z, 0, 0, 0);
        f32x4 s1b = __builtin_amdgcn_mfma_f32_16x16x32_bf16(ka1c, qf1, z, 0, 0, 0);

        float p0a[4], p1a[4], p0b[4], p1b[4];
#pragma unroll
        for (int r = 0; r < 4; r++) {
            p0a[r] = exp2f(s0a[r]);
            p1a[r] = exp2f(s1a[r]);
            p0b[r] = exp2f(s0b[r]);
            p1b[r] = exp2f(s1b[r]);
            lsum0 += p0a[r] + p1a[r];
            lsum1 += p0b[r] + p1b[r];
        }

        unsigned int pk0a[2] = { packbf2(p0a[0], p0a[1]), packbf2(p0a[2], p0a[3]) };
        unsigned int pk1a[2] = { packbf2(p1a[0], p1a[1]), packbf2(p1a[2], p1a[3]) };
        unsigned int pk0b[2] = { packbf2(p0b[0], p0b[1]), packbf2(p0b[2], p0b[3]) };
        unsigned int pk1b[2] = { packbf2(p1b[0], p1b[1]), packbf2(p1b[2], p1b[3]) };
        union { unsigned int u[4]; bf16x8 v; } pfa, pfb;
#pragma unroll
        for (int t = 0; t < 4; t++) {
            const unsigned int loa = (unsigned int)__shfl((int)pk0a[t & 1], src[t], 64);
            const unsigned int hia = (unsigned int)__shfl((int)pk1a[t & 1], src[t], 64);
            const unsigned int lob = (unsigned int)__shfl((int)pk0b[t & 1], src[t], 64);
            const unsigned int hib = (unsigned int)__shfl((int)pk1b[t & 1], src[t], 64);
            pfa.u[t] = (q4 >= 2) ? hia : loa;
            pfb.u[t] = (q4 >= 2) ? hib : lob;
        }

#pragma unroll
        for (int t = 0; t < 4; t++) {
            acc0[t] = __builtin_amdgcn_mfma_f32_16x16x32_bf16(vac[t], pfa.v, acc0[t], 0, 0, 0);
            acc1[t] = __builtin_amdgcn_mfma_f32_16x16x32_bf16(vac[t], pfb.v, acc1[t], 0, 0, 0);
        }
    }

    lsum0 += __shfl_xor(lsum0, 16, 64);
    lsum0 += __shfl_xor(lsum0, 32, 64);
    lsum1 += __shfl_xor(lsum1, 16, 64);
    lsum1 += __shfl_xor(lsum1, 32, 64);

    if (jh == 1) {
#pragma unroll
        for (int t = 0; t < 4; t++)
#pragma unroll
            for (int r = 0; r < 4; r++) {
                accL[(wv * 32 + t * 4 + r) * 64 + lane]      = acc0[t][r];
                accL[(wv * 32 + 16 + t * 4 + r) * 64 + lane] = acc1[t][r];
            }
        if (wv == 0 && lane < 16) lL[lane] = lsum0;
        if (wv == 1 && lane < 16) lL[16 + lane] = lsum1;
    }
    __syncthreads();

    if (jh == 0) {
        const float g = gamma[0];
        const float rl0 = g / (lsum0 + lL[n]);
        const float rl1 = g / (lsum1 + lL[16 + n]);
#pragma unroll
        for (int t = 0; t < 4; t++) {
#pragma unroll
            for (int r = 0; r < 4; r++) {
                const int c = cb + t * 16 + q4 * 4 + r;
                const size_t base = (size_t)(b * CH + c) * NN + i0 + n;
                const float a0 = acc0[t][r] + accL[(wv * 32 + t * 4 + r) * 64 + lane];
                const float a1 = acc1[t][r] + accL[(wv * 32 + 16 + t * 4 + r) * 64 + lane];
                out[base]      = a0 * rl0 + x[base];
                out[base + 16] = a1 * rl1 + x[base + 16];
            }
        }
    }
}

extern "C" void kernel_launch(void* const* d_in, const int* in_sizes, int n_in,
                              void* d_out, int out_size, void* d_ws, size_t ws_size,
                              hipStream_t stream) {
    (void)in_sizes; (void)n_in; (void)out_size; (void)ws_size;
    const float* x     = (const float*)d_in[0];
    const float* Wq    = (const float*)d_in[1];
    const float* bq    = (const float*)d_in[2];
    const float* Wk    = (const float*)d_in[3];
    const float* bk    = (const float*)d_in[4];
    const float* Wv    = (const float*)d_in[5];
    const float* bv    = (const float*)d_in[6];
    const float* Wr    = (const float*)d_in[7];
    // d_in[8] = br: j-constant logit shift -> softmax-invariant, dropped.
    const float* gamma = (const float*)d_in[9];
    float* out = (float*)d_out;
    unsigned short* ws = (unsigned short*)d_ws;

    wrepack_kernel<<<80, 256, 0, stream>>>(Wq, Wk, Wv, ws);
    proj_kernel<<<dim3(64, 8), 256, 0, stream>>>(x, bq, bk, bv, Wr, ws);
    attn_kernel<<<dim3(32, 8), 512, 0, stream>>>(x, gamma, ws, out);
}

// Round 7
// 108.157 us; speedup vs baseline: 2.8205x; 1.0579x over previous
//
#include <hip/hip_runtime.h>
#include <hip/hip_bf16.h>

#define BATCH 8
#define CH    256
#define NN    1024
#define DD    32

// ws layout (bf16 shorts):
//   qT [b][i][d]   (scale*log2e folded)      512 KB
//   kT [b][j][d]   (rp + bias folded)        512 KB
//   v2 [b][jt=32][ct=16][lane=64][jj=8]      4 MB   (MFMA A-frag-ready)
//   wf [mf=20][kc=8][lane=64][jj=8]          160 KB (W in A-frag-ready bf16)
#define QT_OFF 0
#define KT_OFF (BATCH * NN * DD)
#define V_OFF  (2 * BATCH * NN * DD)
#define V2_B   (NN * CH)                       // shorts per batch in v2
#define WF_OFF (V_OFF + BATCH * V2_B)          // 2621440

// 1/sqrt(32) * log2(e): softmax via exp2 (v_exp_f32 is native 2^x)
#define SCALE_Q (0.17677669529663687f * 1.4426950408889634f)
#define INV31 (1.0f / 31.0f)

typedef __attribute__((ext_vector_type(4))) float f32x4;
typedef __attribute__((ext_vector_type(8))) short bf16x8;

__device__ __forceinline__ unsigned int packbf2(float lo, float hi) {
    __hip_bfloat162 h = __float22bfloat162_rn(make_float2(lo, hi));
    union { __hip_bfloat162 h; unsigned int u; } cv; cv.h = h;
    return cv.u;
}
__device__ __forceinline__ unsigned short f2bf(float x) {
    union { float f; unsigned int u; } v; v.f = x;
    return (unsigned short)((v.u + 0x7FFFu + ((v.u >> 16) & 1u)) >> 16);
}

// ---------------------------------------------------------------------------
// Kernel W: repack W_all (320x256 fp32) into MFMA-A-fragment-ready bf16.
// ---------------------------------------------------------------------------
__global__ __launch_bounds__(256) void wrepack_kernel(
    const float* __restrict__ Wq, const float* __restrict__ Wk,
    const float* __restrict__ Wv, unsigned short* __restrict__ ws)
{
    const int gid = blockIdx.x * 256 + threadIdx.x;   // 0..20479
    const int e = gid * 4;
    const int m = e >> 8;
    const int k = e & 255;
    const float* src = (m < 32) ? (Wq + m * CH + k)
                     : (m < 64) ? (Wk + (m - 32) * CH + k)
                                : (Wv + (m - 64) * CH + k);
    const float4 w = *(const float4*)src;
    const int mf = m >> 4, kc = k >> 5;
    const int lf = ((k >> 3) & 3) * 16 + (m & 15);
    const int jj = k & 7;                              // 0 or 4
    uint2 st = { packbf2(w.x, w.y), packbf2(w.z, w.w) };
    *(uint2*)(ws + WF_OFF + ((size_t)(mf * 8 + kc) * 64 + lf) * 8 + jj) = st;
}

// ---------------------------------------------------------------------------
// Kernel P: MFMA projection, double-buffered across kc (x scalars + A-frags
// prefetched one step ahead to break the serial HBM-latency chain).
// ---------------------------------------------------------------------------
__global__ __launch_bounds__(256, 2) void proj_kernel(
    const float* __restrict__ x,
    const float* __restrict__ bq, const float* __restrict__ bk,
    const float* __restrict__ bv, const float* __restrict__ Wr,
    unsigned short* __restrict__ ws)
{
    const int nt   = blockIdx.x;   // 0..63
    const int b    = blockIdx.y;   // 0..7
    const int tid  = threadIdx.x;
    const int wv   = tid >> 6;     // 0..3 (m-group)
    const int lane = tid & 63;
    const int n16  = lane & 15;
    const int q4   = lane >> 4;
    const int n    = nt * 16 + n16;

    f32x4 acc[5];
#pragma unroll
    for (int t = 0; t < 5; t++) acc[t] = (f32x4){0.f, 0.f, 0.f, 0.f};

    const unsigned short* wfl = ws + WF_OFF + (size_t)lane * 8;
    const float* xb = x + (size_t)b * CH * NN + n;

    float  bx[2][8];
    bf16x8 af[2][5];
    // stage 0: kc = 0
#pragma unroll
    for (int jj = 0; jj < 8; jj++)
        bx[0][jj] = xb[(size_t)(q4 * 8 + jj) * NN];
#pragma unroll
    for (int t = 0; t < 5; t++)
        af[0][t] = *(const bf16x8*)(wfl + (size_t)((wv * 5 + t) * 8) * 512);

#pragma unroll
    for (int kc = 0; kc < 8; kc++) {
        const int s = kc & 1;
        if (kc < 7) {
            const int kofs = (kc + 1) * 32 + q4 * 8;
#pragma unroll
            for (int jj = 0; jj < 8; jj++)
                bx[s ^ 1][jj] = xb[(size_t)(kofs + jj) * NN];
#pragma unroll
            for (int t = 0; t < 5; t++)
                af[s ^ 1][t] = *(const bf16x8*)(wfl + (size_t)((wv * 5 + t) * 8 + kc + 1) * 512);
        }
        union { unsigned int u[4]; bf16x8 v; } bf;
#pragma unroll
        for (int p = 0; p < 4; p++) bf.u[p] = packbf2(bx[s][2 * p], bx[s][2 * p + 1]);
#pragma unroll
        for (int t = 0; t < 5; t++)
            acc[t] = __builtin_amdgcn_mfma_f32_16x16x32_bf16(af[s][t], bf.v, acc[t], 0, 0, 0);
    }

    const int jt  = n >> 5;
    const int q4p = (n >> 3) & 3;
    const int jj  = n & 7;
#pragma unroll
    for (int t = 0; t < 5; t++) {
        const int mf = wv * 5 + t;
        const int mb = mf * 16 + q4 * 4;
        if (mb < 32) {
            const float r0 = (acc[t][0] + bq[mb + 0]) * SCALE_Q;
            const float r1 = (acc[t][1] + bq[mb + 1]) * SCALE_Q;
            const float r2 = (acc[t][2] + bq[mb + 2]) * SCALE_Q;
            const float r3 = (acc[t][3] + bq[mb + 3]) * SCALE_Q;
            uint2 st = { packbf2(r0, r1), packbf2(r2, r3) };
            *(uint2*)(ws + QT_OFF + (size_t)(b * NN + n) * DD + mb) = st;
        } else if (mb < 64) {
            const int d = mb - 32;
            const float An = (float)(n >> 5) * INV31;
            const float Bn = (float)(n & 31) * INV31;
            float r[4];
#pragma unroll
            for (int rr = 0; rr < 4; rr++)
                r[rr] = acc[t][rr] + bk[d + rr] - An * Wr[2 * (d + rr)] - Bn * Wr[2 * (d + rr) + 1];
            uint2 st = { packbf2(r[0], r[1]), packbf2(r[2], r[3]) };
            *(uint2*)(ws + KT_OFF + (size_t)(b * NN + n) * DD + d) = st;
        } else {
            const int c = mb - 64;
#pragma unroll
            for (int rr = 0; rr < 4; rr++) {
                const int cc = c + rr;
                const size_t off = V_OFF + (size_t)b * V2_B
                                 + (size_t)jt * 8192 + (size_t)(cc >> 4) * 512
                                 + (size_t)(q4p * 16 + (cc & 15)) * 8 + jj;
                ws[off] = f2bf(acc[t][rr] + bv[cc]);
            }
        }
    }
}

// ---------------------------------------------------------------------------
// Kernel B: MFMA flash attention, occupancy-shaped: 1024 blocks x 256 thr,
// block = (b, i-group of 16, c-half); 4 waves = (j-half) x (c-sub-64).
// Grid (8,128): linear block id === b (mod 8) -> all blocks of a batch land
// on one XCD, keeping that batch's K/V L2-resident (XCD-affinity swizzle).
// No-max softmax via exp2, 1-deep prefetch, single barrier.
// ---------------------------------------------------------------------------
__global__ __launch_bounds__(256, 4) void attn_kernel(
    const float* __restrict__ x,
    const float* __restrict__ gamma,
    const unsigned short* __restrict__ ws,
    float* __restrict__ out)
{
    const int b    = blockIdx.x;        // 0..7  (XCD affinity)
    const int by   = blockIdx.y;        // 0..127
    const int ig   = by >> 1;           // i-group 0..63
    const int cs   = by & 1;            // c-half
    const int tid  = threadIdx.x;
    const int jh   = tid >> 7;          // j-half (waves 0,1 vs 2,3)
    const int cw   = (tid >> 6) & 1;    // c-sub within half
    const int lane = tid & 63;
    const int n    = lane & 15;         // col index: i (within tile)
    const int q4   = lane >> 4;
    const int i0   = ig * 16;
    const int cb   = cs * 128 + cw * 64;

    __shared__ float accL[2 * 16 * 64];  // 8 KB: [cw][reg][lane]
    __shared__ float lL[16];

    const unsigned short* qT = ws + QT_OFF + (size_t)b * NN * DD;
    const unsigned short* kT = ws + KT_OFF + (size_t)b * NN * DD + (size_t)jh * 512 * DD;
    const unsigned short* vb = ws + V_OFF + (size_t)b * V2_B
                             + (size_t)jh * 16 * 8192 + (size_t)(cb >> 4) * 512
                             + (size_t)lane * 8;

    const bf16x8 qf = *(const bf16x8*)(qT + (size_t)(i0 + n) * DD + q4 * 8);

    f32x4 acc[4];
#pragma unroll
    for (int t = 0; t < 4; t++) acc[t] = (f32x4){0.f, 0.f, 0.f, 0.f};
    float lsum = 0.f;

    // 1-deep prefetch (over-reads past region end land inside ws — harmless)
    bf16x8 ka0 = *(const bf16x8*)(kT + (size_t)(n) * DD + q4 * 8);
    bf16x8 ka1 = *(const bf16x8*)(kT + (size_t)(16 + n) * DD + q4 * 8);
    bf16x8 va[4];
#pragma unroll
    for (int t = 0; t < 4; t++)
        va[t] = *(const bf16x8*)(vb + t * 512);

    const int qh2 = (q4 & 1) * 2;
    int src[4];
#pragma unroll
    for (int t = 0; t < 4; t++) src[t] = (qh2 + (t >> 1)) * 16 + n;

#pragma unroll 4
    for (int ch = 0; ch < 16; ch++) {
        const bf16x8 ka0c = ka0, ka1c = ka1;
        bf16x8 vac[4];
#pragma unroll
        for (int t = 0; t < 4; t++) vac[t] = va[t];

        {   // prefetch next chunk
            const int j0 = (ch + 1) * 32;
            ka0 = *(const bf16x8*)(kT + (size_t)(j0 + n) * DD + q4 * 8);
            ka1 = *(const bf16x8*)(kT + (size_t)(j0 + 16 + n) * DD + q4 * 8);
#pragma unroll
            for (int t = 0; t < 4; t++)
                va[t] = *(const bf16x8*)(vb + (ch + 1) * 8192 + t * 512);
        }

        const f32x4 z = {0.f, 0.f, 0.f, 0.f};
        f32x4 s0 = __builtin_amdgcn_mfma_f32_16x16x32_bf16(ka0c, qf, z, 0, 0, 0);
        f32x4 s1 = __builtin_amdgcn_mfma_f32_16x16x32_bf16(ka1c, qf, z, 0, 0, 0);

        float p0[4], p1[4];
#pragma unroll
        for (int r = 0; r < 4; r++) {
            p0[r] = exp2f(s0[r]);
            p1[r] = exp2f(s1[r]);
            lsum += p0[r] + p1[r];
        }

        unsigned int pk0[2] = { packbf2(p0[0], p0[1]), packbf2(p0[2], p0[3]) };
        unsigned int pk1[2] = { packbf2(p1[0], p1[1]), packbf2(p1[2], p1[3]) };
        union { unsigned int u[4]; bf16x8 v; } pf;
#pragma unroll
        for (int t = 0; t < 4; t++) {
            const unsigned int lo = (unsigned int)__shfl((int)pk0[t & 1], src[t], 64);
            const unsigned int hi = (unsigned int)__shfl((int)pk1[t & 1], src[t], 64);
            pf.u[t] = (q4 >= 2) ? hi : lo;
        }

#pragma unroll
        for (int t = 0; t < 4; t++)
            acc[t] = __builtin_amdgcn_mfma_f32_16x16x32_bf16(vac[t], pf.v, acc[t], 0, 0, 0);
    }

    lsum += __shfl_xor(lsum, 16, 64);
    lsum += __shfl_xor(lsum, 32, 64);

    if (jh == 1) {
#pragma unroll
        for (int t = 0; t < 4; t++)
#pragma unroll
            for (int r = 0; r < 4; r++)
                accL[(cw * 16 + t * 4 + r) * 64 + lane] = acc[t][r];
        if (cw == 0 && lane < 16) lL[lane] = lsum;
    }
    __syncthreads();

    if (jh == 0) {
        const float rl = gamma[0] / (lsum + lL[n]);
#pragma unroll
        for (int t = 0; t < 4; t++) {
#pragma unroll
            for (int r = 0; r < 4; r++) {
                const int c = cb + t * 16 + q4 * 4 + r;
                const size_t idx = (size_t)(b * CH + c) * NN + i0 + n;
                const float a = acc[t][r] + accL[(cw * 16 + t * 4 + r) * 64 + lane];
                out[idx] = a * rl + x[idx];
            }
        }
    }
}

extern "C" void kernel_launch(void* const* d_in, const int* in_sizes, int n_in,
                              void* d_out, int out_size, void* d_ws, size_t ws_size,
                              hipStream_t stream) {
    (void)in_sizes; (void)n_in; (void)out_size; (void)ws_size;
    const float* x     = (const float*)d_in[0];
    const float* Wq    = (const float*)d_in[1];
    const float* bq    = (const float*)d_in[2];
    const float* Wk    = (const float*)d_in[3];
    const float* bk    = (const float*)d_in[4];
    const float* Wv    = (const float*)d_in[5];
    const float* bv    = (const float*)d_in[6];
    const float* Wr    = (const float*)d_in[7];
    // d_in[8] = br: j-constant logit shift -> softmax-invariant, dropped.
    const float* gamma = (const float*)d_in[9];
    float* out = (float*)d_out;
    unsigned short* ws = (unsigned short*)d_ws;

    wrepack_kernel<<<80, 256, 0, stream>>>(Wq, Wk, Wv, ws);
    proj_kernel<<<dim3(64, 8), 256, 0, stream>>>(x, bq, bk, bv, Wr, ws);
    attn_kernel<<<dim3(8, 128), 256, 0, stream>>>(x, gamma, ws, out);
}